// Round 3
// baseline (157.457 us; speedup 1.0000x reference)
//
#include <hip/hip_runtime.h>
#include <hip/hip_bf16.h>

typedef _Float16 h4 __attribute__((ext_vector_type(4)));
typedef _Float16 h8 __attribute__((ext_vector_type(8)));
typedef float f32x4 __attribute__((ext_vector_type(4)));

#define CIN 128
#define COUT 256
#define HW 64
#define KK 9
#define KDIM (CIN*KK)   // 1152
#define NCHUNK (KDIM/32) // 36

// ---------------- prep: om_w transpose (f32) ----------------
// omwT[(c*9+k)*27 + oc] = om_w[oc][c][k]
__global__ void k_prep_omw(const float* __restrict__ om_w, float* __restrict__ omwT) {
    int d = blockIdx.x * 256 + threadIdx.x;
    if (d >= 27 * KDIM) return;
    int r = d / 27, oc = d - r * 27;
    omwT[d] = om_w[oc * KDIM + r];
}

// ---------------- prep: weight -> fp16 MFMA A-frag layout ----------------
// Wf[(((kch*16 + of)*64 + lane)*8 + e)] = fp16( W[o=of*16+(lane&15)][kc=kch*32+(lane>>4)*8+e] )
// with kc = k*128 + c  (k outer, c inner), W[o][c][k] row-major from reference.
__global__ void k_prep_wf(const float* __restrict__ wgt, unsigned short* __restrict__ Wf) {
    int f = blockIdx.x * 256 + threadIdx.x;   // exactly 294912 threads
    int e = f & 7, l = (f >> 3) & 63, of = (f >> 9) & 15, kch = f >> 13;
    int o = of * 16 + (l & 15);
    int kc = kch * 32 + (l >> 4) * 8 + e;
    int k = kc >> 7, c = kc & 127;
    _Float16 hv = (_Float16)wgt[(size_t)o * KDIM + c * 9 + k];
    Wf[f] = *(unsigned short*)&hv;
}

// ---------------- transpose x -> channels-last fp16 ----------------
// xT[((b*64+y)*64+x)*128 + c] = fp16(x[b][c][y][x])
__global__ __launch_bounds__(256) void k_transpose(const float* __restrict__ x,
                                                   unsigned short* __restrict__ xT) {
    __shared__ unsigned short tile[64][132];
    const int b = blockIdx.x >> 6, y = blockIdx.x & 63;
    const float* xp = x + (size_t)b * CIN * 4096 + y * 64;
    const int w = threadIdx.x & 63, cg = threadIdx.x >> 6;
#pragma unroll
    for (int cc = 0; cc < CIN; cc += 4) {
        int c = cc + cg;
        _Float16 hv = (_Float16)xp[(size_t)c * 4096 + w];
        tile[w][c] = *(unsigned short*)&hv;
    }
    __syncthreads();
    unsigned short* orow = xT + (size_t)(b * 4096 + y * 64) * CIN;
#pragma unroll
    for (int i = 0; i < 8; ++i) {
        int j = threadIdx.x + i * 256;          // half4 index in [0,2048)
        int w2 = j >> 5, c2 = (j & 31) * 4;
        ushort4 v = *(ushort4*)&tile[w2][c2];
        ((ushort4*)orow)[j] = v;
    }
}

// ---------------- offset conv (f32, full precision) ----------------
// om[((b*64+h)*64+w)*27 + oc]
__global__ __launch_bounds__(256) void k_omconv(const float* __restrict__ x,
                                                const float* __restrict__ omwT,
                                                const float* __restrict__ om_b,
                                                float* __restrict__ om) {
    const int b = blockIdx.x >> 6, h = blockIdx.x & 63;
    const int w = threadIdx.x & 63;
    const int cg = __builtin_amdgcn_readfirstlane(threadIdx.x >> 6); // 0..3, wave-uniform
    float acc[27];
#pragma unroll
    for (int i = 0; i < 27; ++i) acc[i] = 0.f;
    const float* xb = x + (size_t)b * CIN * 4096;
    const int cbase = cg * 32;
    for (int c = 0; c < 32; ++c) {
        const int cc = cbase + c;
        const float* xc = xb + (size_t)cc * 4096;
        const float* wtc = omwT + cc * 9 * 27;
#pragma unroll
        for (int ky = 0; ky < 3; ++ky) {
            const int y = h + ky - 1;
            float v0 = 0.f, v1 = 0.f, v2 = 0.f;
            if ((unsigned)y < 64u) {
                const float* xr = xc + y * 64;
                v1 = xr[w];
                if (w >= 1) v0 = xr[w - 1];
                if (w <= 62) v2 = xr[w + 1];
            }
            const float* wt = wtc + ky * 3 * 27;
#pragma unroll
            for (int oc = 0; oc < 27; ++oc)
                acc[oc] += v0 * wt[oc] + v1 * wt[27 + oc] + v2 * wt[54 + oc];
        }
    }
    __shared__ float red[4][64][27];
#pragma unroll
    for (int i = 0; i < 27; ++i) red[cg][w][i] = acc[i];
    __syncthreads();
    float* omr = om + (size_t)(b * 64 + h) * 64 * 27;
    for (int j = threadIdx.x; j < 64 * 27; j += 256) {
        int pw = j / 27, oc = j - pw * 27;
        omr[j] = red[0][pw][oc] + red[1][pw][oc] + red[2][pw][oc] + red[3][pw][oc] + om_b[oc];
    }
}

// ---------------- fused gather + MFMA GEMM ----------------
__global__ __launch_bounds__(512) void k_main(const unsigned short* __restrict__ xT_u,
                                              const float* __restrict__ om,
                                              const unsigned short* __restrict__ Wf_u,
                                              const float* __restrict__ bias,
                                              float* __restrict__ out) {
    const int b = blockIdx.x >> 6, h = blockIdx.x & 63;
    const int tid = threadIdx.x;

    __shared__ int   s_off[4][576];
    __shared__ float s_wt[4][576];
    __shared__ _Float16 s_tile[64][40];   // [p][c_local], padded stride

    // --- sampling metadata for all (k, p) ---
    const float* omr = om + (size_t)(b * 64 + h) * 64 * 27;
    for (int e = tid; e < 576; e += 512) {
        int k = e >> 6, p = e & 63;
        float offx = omr[p * 27 + k];
        float offy = omr[p * 27 + 9 + k];
        float mv   = omr[p * 27 + 18 + k];
        float mask = 1.f / (1.f + __expf(-mv));
        int ky = k / 3, kx = k - ky * 3;
        const float SC = 64.f / 63.f;
        float ix = ((float)(p + kx - 2) + offx) * SC - 0.5f;
        float iy = ((float)(h + ky - 2) + offy) * SC - 0.5f;
        float fx0 = floorf(ix), fy0 = floorf(iy);
        float wx1 = ix - fx0, wx0 = 1.f - wx1;
        float wy1 = iy - fy0, wy0 = 1.f - wy1;
        int x0 = (int)fx0, y0 = (int)fy0;
        int x1 = x0 + 1, y1 = y0 + 1;
        bool vx0 = (unsigned)x0 < 64u, vx1 = (unsigned)x1 < 64u;
        bool vy0 = (unsigned)y0 < 64u, vy1 = (unsigned)y1 < 64u;
        int xc0 = min(max(x0, 0), 63), xc1 = min(max(x1, 0), 63);
        int yc0 = min(max(y0, 0), 63), yc1 = min(max(y1, 0), 63);
        s_off[0][e] = (yc0 * 64 + xc0) * CIN;
        s_off[1][e] = (yc0 * 64 + xc1) * CIN;
        s_off[2][e] = (yc1 * 64 + xc0) * CIN;
        s_off[3][e] = (yc1 * 64 + xc1) * CIN;
        s_wt[0][e] = (vy0 && vx0) ? wy0 * wx0 * mask : 0.f;
        s_wt[1][e] = (vy0 && vx1) ? wy0 * wx1 * mask : 0.f;
        s_wt[2][e] = (vy1 && vx0) ? wy1 * wx0 * mask : 0.f;
        s_wt[3][e] = (vy1 && vx1) ? wy1 * wx1 * mask : 0.f;
    }
    __syncthreads();

    const int p  = tid >> 3;      // gather position 0..63
    const int ci = tid & 7;       // 4-channel subgroup
    const _Float16* xb = (const _Float16*)xT_u + (size_t)b * (4096 * CIN);

    const int wv = tid >> 6;      // wave 0..7
    const int lane = tid & 63;
    const int khalf = lane >> 4, lr = lane & 15;

    f32x4 acc[2][4];
#pragma unroll
    for (int i = 0; i < 2; ++i)
#pragma unroll
        for (int j = 0; j < 4; ++j) acc[i][j] = (f32x4){0.f, 0.f, 0.f, 0.f};

    for (int k = 0; k < 9; ++k) {
        const int e = k * 64 + p;
        const int o00 = s_off[0][e], o01 = s_off[1][e], o10 = s_off[2][e], o11 = s_off[3][e];
        const float m00 = s_wt[0][e], m01 = s_wt[1][e], m10 = s_wt[2][e], m11 = s_wt[3][e];
#pragma unroll
        for (int cg = 0; cg < 4; ++cg) {
            const int c0 = cg * 32 + ci * 4;
            h4 v00 = *(const h4*)(xb + o00 + c0);
            h4 v01 = *(const h4*)(xb + o01 + c0);
            h4 v10 = *(const h4*)(xb + o10 + c0);
            h4 v11 = *(const h4*)(xb + o11 + c0);
            h4 pk;
#pragma unroll
            for (int j = 0; j < 4; ++j) {
                float r = m00 * (float)v00[j] + m01 * (float)v01[j]
                        + m10 * (float)v10[j] + m11 * (float)v11[j];
                pk[j] = (_Float16)r;
            }
            __syncthreads();   // previous chunk's MFMA reads done
            *(h4*)&s_tile[p][ci * 4] = pk;
            __syncthreads();   // tile ready
            const int kch = k * 4 + cg;
            const h8* Wf8 = (const h8*)Wf_u;
            h8 a0 = Wf8[(kch * 16 + wv * 2 + 0) * 64 + lane];
            h8 a1 = Wf8[(kch * 16 + wv * 2 + 1) * 64 + lane];
            h8 bf[4];
#pragma unroll
            for (int pf = 0; pf < 4; ++pf)
                bf[pf] = *(const h8*)&s_tile[pf * 16 + lr][khalf * 8];
#pragma unroll
            for (int pf = 0; pf < 4; ++pf) {
                acc[0][pf] = __builtin_amdgcn_mfma_f32_16x16x32_f16(a0, bf[pf], acc[0][pf], 0, 0, 0);
                acc[1][pf] = __builtin_amdgcn_mfma_f32_16x16x32_f16(a1, bf[pf], acc[1][pf], 0, 0, 0);
            }
        }
    }

    // epilogue: C[o = wv*32 + i*16 + khalf*4 + r][p = pf*16 + lr]
    float* outb = out + (size_t)b * COUT * 4096 + h * 64;
#pragma unroll
    for (int i = 0; i < 2; ++i) {
#pragma unroll
        for (int r = 0; r < 4; ++r) {
            const int o = wv * 32 + i * 16 + khalf * 4 + r;
            const float bo = bias[o];
            float* orow = outb + (size_t)o * 4096;
#pragma unroll
            for (int pf = 0; pf < 4; ++pf)
                orow[pf * 16 + lr] = acc[i][pf][r] + bo;
        }
    }
}

extern "C" void kernel_launch(void* const* d_in, const int* in_sizes, int n_in,
                              void* d_out, int out_size, void* d_ws, size_t ws_size,
                              hipStream_t stream) {
    const float* x    = (const float*)d_in[0];
    const float* om_w = (const float*)d_in[1];
    const float* om_b = (const float*)d_in[2];
    const float* wgt  = (const float*)d_in[3];
    const float* bias = (const float*)d_in[4];
    float* out = (float*)d_out;

    char* ws = (char*)d_ws;
    unsigned short* xT = (unsigned short*)ws;                       // 4*4096*128*2   = 4194304 B
    float* om          = (float*)(ws + 4194304);                    // 4*4096*27*4    = 1769472 B
    float* omwT        = (float*)(ws + 4194304 + 1769472);          // 1152*27*4      =  124416 B
    unsigned short* Wf = (unsigned short*)(ws + 4194304 + 1769472 + 124416); // 294912*2 = 589824 B

    k_prep_omw <<<(27 * KDIM + 255) / 256, 256, 0, stream>>>(om_w, omwT);
    k_prep_wf  <<<(COUT * KDIM) / 256, 256, 0, stream>>>(wgt, Wf);
    k_transpose<<<256, 256, 0, stream>>>(x, xT);
    k_omconv   <<<256, 256, 0, stream>>>(x, omwT, om_b, om);
    k_main     <<<256, 512, 0, stream>>>(xT, om, Wf, bias, out);
}

// Round 5
// 65.414 us; speedup vs baseline: 2.4071x; 2.4071x over previous
//
#include <hip/hip_runtime.h>
#include <hip/hip_bf16.h>

typedef _Float16 h4 __attribute__((ext_vector_type(4)));
typedef _Float16 h8 __attribute__((ext_vector_type(8)));
typedef float f32x4 __attribute__((ext_vector_type(4)));

#define CIN 128
#define COUT 256
#define HW 64
#define KK 9
#define KDIM (CIN*KK)   // 1152
#define NCHUNK (KDIM/32) // 36

// ---------------- prep: main weight -> fp16 MFMA A-frag layout ----------------
// Wf[(((kch*16 + of)*64 + lane)*8 + e)] = fp16( W[o=of*16+(lane&15)][kc=kch*32+(lane>>4)*8+e] )
// with kc = k*128 + c  (k outer, c inner), W[o][c][k] row-major from reference.
__global__ void k_prep_wf(const float* __restrict__ wgt, unsigned short* __restrict__ Wf) {
    int f = blockIdx.x * 256 + threadIdx.x;   // exactly 294912 threads
    int e = f & 7, l = (f >> 3) & 63, of = (f >> 9) & 15, kch = f >> 13;
    int o = of * 16 + (l & 15);
    int kc = kch * 32 + (l >> 4) * 8 + e;
    int k = kc >> 7, c = kc & 127;
    _Float16 hv = (_Float16)wgt[(size_t)o * KDIM + c * 9 + k];
    Wf[f] = *(unsigned short*)&hv;
}

// ---------------- prep: om_w -> fp16 MFMA A-frag layout (M padded 27->32) -------
// omWf[(((kch*2 + of)*64 + l)*8 + e)] = fp16( om_w[o=of*16+(l&15)][c][k] ), 0 if o>=27
// c = (kch&3)*32 + (l>>4)*8 + e, k = kch>>2.
__global__ void k_prep_omwf(const float* __restrict__ om_w, unsigned short* __restrict__ omWf) {
    int f = blockIdx.x * 256 + threadIdx.x;   // exactly 36864 threads
    int e = f & 7, l = (f >> 3) & 63, of = (f >> 9) & 1, kch = f >> 10;
    int o = of * 16 + (l & 15);
    int c = (kch & 3) * 32 + (l >> 4) * 8 + e;
    int k = kch >> 2;
    float v = (o < 27) ? om_w[(size_t)o * KDIM + c * 9 + k] : 0.f;
    _Float16 hv = (_Float16)v;
    omWf[f] = *(unsigned short*)&hv;
}

// ---------------- transpose x -> channels-last fp16 ----------------
// xT[((b*64+y)*64+x)*128 + c] = fp16(x[b][c][y][x])
__global__ __launch_bounds__(256) void k_transpose(const float* __restrict__ x,
                                                   unsigned short* __restrict__ xT) {
    __shared__ unsigned short tile[64][132];
    const int b = blockIdx.x >> 6, y = blockIdx.x & 63;
    const float* xp = x + (size_t)b * CIN * 4096 + y * 64;
    const int w = threadIdx.x & 63, cg = threadIdx.x >> 6;
#pragma unroll
    for (int cc = 0; cc < CIN; cc += 4) {
        int c = cc + cg;
        _Float16 hv = (_Float16)xp[(size_t)c * 4096 + w];
        tile[w][c] = *(unsigned short*)&hv;
    }
    __syncthreads();
    unsigned short* orow = xT + (size_t)(b * 4096 + y * 64) * CIN;
#pragma unroll
    for (int i = 0; i < 8; ++i) {
        int j = threadIdx.x + i * 256;          // half4 index in [0,2048)
        int w2 = j >> 5, c2 = (j & 31) * 4;
        ushort4 v = *(ushort4*)&tile[w2][c2];
        ((ushort4*)orow)[j] = v;
    }
}

// ---------------- offset conv via MFMA (fp16 in, f32 acc) ----------------
// om[((b*64+h)*64+p)*27 + oc] = conv3x3(x, om_w) + om_b
// One block per (b,h); 4 waves x 16 positions; im2col B-frags loaded
// directly from xT with tap shift + zero padding at edges.
__global__ __launch_bounds__(256) void k_omconv(const unsigned short* __restrict__ xT_u,
                                                const unsigned short* __restrict__ omWf_u,
                                                const float* __restrict__ om_b,
                                                float* __restrict__ om) {
    const int b = blockIdx.x >> 6, h = blockIdx.x & 63;
    const int tid = threadIdx.x;
    const int wv = tid >> 6, lane = tid & 63;
    const int khalf = lane >> 4, lr = lane & 15;
    const int p = wv * 16 + lr;                 // this lane's B-column (position)
    const _Float16* xb = (const _Float16*)xT_u + (size_t)b * 4096 * CIN;
    const h8* Af = (const h8*)omWf_u;

    f32x4 acc0 = (f32x4){0.f, 0.f, 0.f, 0.f};
    f32x4 acc1 = (f32x4){0.f, 0.f, 0.f, 0.f};

#pragma unroll
    for (int k = 0; k < 9; ++k) {
        const int ky = k / 3, kx = k - ky * 3;
        const int y = h + ky - 1, xq = p + kx - 1;
        const bool valid = ((unsigned)y < 64u) && ((unsigned)xq < 64u);
        const _Float16* src = xb + ((y * 64 + xq) * CIN);
#pragma unroll
        for (int cg = 0; cg < 4; ++cg) {
            h8 bf = {};
            if (valid) bf = *(const h8*)(src + cg * 32 + khalf * 8);
            const int kch = k * 4 + cg;
            h8 a0 = Af[(kch * 2 + 0) * 64 + lane];
            h8 a1 = Af[(kch * 2 + 1) * 64 + lane];
            acc0 = __builtin_amdgcn_mfma_f32_16x16x32_f16(a0, bf, acc0, 0, 0, 0);
            acc1 = __builtin_amdgcn_mfma_f32_16x16x32_f16(a1, bf, acc1, 0, 0, 0);
        }
    }

    // C layout: col = lane&15 (position), row = khalf*4 + r (+16 for acc1)
    float* omr = om + ((size_t)(b * 64 + h) * 64 + p) * 27;
#pragma unroll
    for (int r = 0; r < 4; ++r) {
        int row0 = khalf * 4 + r;
        omr[row0] = acc0[r] + om_b[row0];
        int row1 = 16 + khalf * 4 + r;
        if (row1 < 27) omr[row1] = acc1[r] + om_b[row1];
    }
}

// ---------------- fused gather + MFMA GEMM ----------------
__global__ __launch_bounds__(512) void k_main(const unsigned short* __restrict__ xT_u,
                                              const float* __restrict__ om,
                                              const unsigned short* __restrict__ Wf_u,
                                              const float* __restrict__ bias,
                                              float* __restrict__ out) {
    const int b = blockIdx.x >> 6, h = blockIdx.x & 63;
    const int tid = threadIdx.x;

    __shared__ int   s_off[4][576];
    __shared__ float s_wt[4][576];
    __shared__ _Float16 s_tile[64][40];   // [p][c_local], padded stride

    // --- sampling metadata for all (k, p) ---
    const float* omr = om + (size_t)(b * 64 + h) * 64 * 27;
    for (int e = tid; e < 576; e += 512) {
        int k = e >> 6, p = e & 63;
        float offx = omr[p * 27 + k];
        float offy = omr[p * 27 + 9 + k];
        float mv   = omr[p * 27 + 18 + k];
        float mask = 1.f / (1.f + __expf(-mv));
        int ky = k / 3, kx = k - ky * 3;
        const float SC = 64.f / 63.f;
        float ix = ((float)(p + kx - 2) + offx) * SC - 0.5f;
        float iy = ((float)(h + ky - 2) + offy) * SC - 0.5f;
        float fx0 = floorf(ix), fy0 = floorf(iy);
        float wx1 = ix - fx0, wx0 = 1.f - wx1;
        float wy1 = iy - fy0, wy0 = 1.f - wy1;
        int x0 = (int)fx0, y0 = (int)fy0;
        int x1 = x0 + 1, y1 = y0 + 1;
        bool vx0 = (unsigned)x0 < 64u, vx1 = (unsigned)x1 < 64u;
        bool vy0 = (unsigned)y0 < 64u, vy1 = (unsigned)y1 < 64u;
        int xc0 = min(max(x0, 0), 63), xc1 = min(max(x1, 0), 63);
        int yc0 = min(max(y0, 0), 63), yc1 = min(max(y1, 0), 63);
        s_off[0][e] = (yc0 * 64 + xc0) * CIN;
        s_off[1][e] = (yc0 * 64 + xc1) * CIN;
        s_off[2][e] = (yc1 * 64 + xc0) * CIN;
        s_off[3][e] = (yc1 * 64 + xc1) * CIN;
        s_wt[0][e] = (vy0 && vx0) ? wy0 * wx0 * mask : 0.f;
        s_wt[1][e] = (vy0 && vx1) ? wy0 * wx1 * mask : 0.f;
        s_wt[2][e] = (vy1 && vx0) ? wy1 * wx0 * mask : 0.f;
        s_wt[3][e] = (vy1 && vx1) ? wy1 * wx1 * mask : 0.f;
    }
    __syncthreads();

    const int p  = tid >> 3;      // gather position 0..63
    const int ci = tid & 7;       // 4-channel subgroup
    const _Float16* xb = (const _Float16*)xT_u + (size_t)b * (4096 * CIN);

    const int wv = tid >> 6;      // wave 0..7
    const int lane = tid & 63;
    const int khalf = lane >> 4, lr = lane & 15;

    f32x4 acc[2][4];
#pragma unroll
    for (int i = 0; i < 2; ++i)
#pragma unroll
        for (int j = 0; j < 4; ++j) acc[i][j] = (f32x4){0.f, 0.f, 0.f, 0.f};

    for (int k = 0; k < 9; ++k) {
        const int e = k * 64 + p;
        const int o00 = s_off[0][e], o01 = s_off[1][e], o10 = s_off[2][e], o11 = s_off[3][e];
        const float m00 = s_wt[0][e], m01 = s_wt[1][e], m10 = s_wt[2][e], m11 = s_wt[3][e];
#pragma unroll
        for (int cg = 0; cg < 4; ++cg) {
            const int c0 = cg * 32 + ci * 4;
            h4 v00 = *(const h4*)(xb + o00 + c0);
            h4 v01 = *(const h4*)(xb + o01 + c0);
            h4 v10 = *(const h4*)(xb + o10 + c0);
            h4 v11 = *(const h4*)(xb + o11 + c0);
            h4 pk;
#pragma unroll
            for (int j = 0; j < 4; ++j) {
                float r = m00 * (float)v00[j] + m01 * (float)v01[j]
                        + m10 * (float)v10[j] + m11 * (float)v11[j];
                pk[j] = (_Float16)r;
            }
            __syncthreads();   // previous chunk's MFMA reads done
            *(h4*)&s_tile[p][ci * 4] = pk;
            __syncthreads();   // tile ready
            const int kch = k * 4 + cg;
            const h8* Wf8 = (const h8*)Wf_u;
            h8 a0 = Wf8[(kch * 16 + wv * 2 + 0) * 64 + lane];
            h8 a1 = Wf8[(kch * 16 + wv * 2 + 1) * 64 + lane];
            h8 bf[4];
#pragma unroll
            for (int pf = 0; pf < 4; ++pf)
                bf[pf] = *(const h8*)&s_tile[pf * 16 + lr][khalf * 8];
#pragma unroll
            for (int pf = 0; pf < 4; ++pf) {
                acc[0][pf] = __builtin_amdgcn_mfma_f32_16x16x32_f16(a0, bf[pf], acc[0][pf], 0, 0, 0);
                acc[1][pf] = __builtin_amdgcn_mfma_f32_16x16x32_f16(a1, bf[pf], acc[1][pf], 0, 0, 0);
            }
        }
    }

    // epilogue: C[o = wv*32 + i*16 + khalf*4 + r][p = pf*16 + lr]
    float* outb = out + (size_t)b * COUT * 4096 + h * 64;
#pragma unroll
    for (int i = 0; i < 2; ++i) {
#pragma unroll
        for (int r = 0; r < 4; ++r) {
            const int o = wv * 32 + i * 16 + khalf * 4 + r;
            const float bo = bias[o];
            float* orow = outb + (size_t)o * 4096;
#pragma unroll
            for (int pf = 0; pf < 4; ++pf)
                orow[pf * 16 + lr] = acc[i][pf][r] + bo;
        }
    }
}

extern "C" void kernel_launch(void* const* d_in, const int* in_sizes, int n_in,
                              void* d_out, int out_size, void* d_ws, size_t ws_size,
                              hipStream_t stream) {
    const float* x    = (const float*)d_in[0];
    const float* om_w = (const float*)d_in[1];
    const float* om_b = (const float*)d_in[2];
    const float* wgt  = (const float*)d_in[3];
    const float* bias = (const float*)d_in[4];
    float* out = (float*)d_out;

    char* ws = (char*)d_ws;
    unsigned short* xT   = (unsigned short*)ws;                      // 4*4096*128*2 = 4194304 B
    float* om            = (float*)(ws + 4194304);                   // 4*4096*27*4  = 1769472 B
    unsigned short* Wf   = (unsigned short*)(ws + 4194304 + 1769472);            // 294912*2 = 589824 B
    unsigned short* omWf = (unsigned short*)(ws + 4194304 + 1769472 + 589824);   // 36864*2  =  73728 B

    k_prep_wf   <<<(COUT * KDIM) / 256, 256, 0, stream>>>(wgt, Wf);
    k_prep_omwf <<<(2 * 16 * KDIM) / 256, 256, 0, stream>>>(om_w, omWf);
    k_transpose <<<256, 256, 0, stream>>>(x, xT);
    k_omconv    <<<256, 256, 0, stream>>>(xT, omWf, om_b, om);
    k_main      <<<256, 512, 0, stream>>>(xT, om, Wf, bias, out);
}

// Round 6
// 55.320 us; speedup vs baseline: 2.8463x; 1.1824x over previous
//
#include <hip/hip_runtime.h>
#include <hip/hip_bf16.h>

typedef _Float16 h4 __attribute__((ext_vector_type(4)));
typedef _Float16 h8 __attribute__((ext_vector_type(8)));
typedef float f32x4 __attribute__((ext_vector_type(4)));

#define CIN 128
#define COUT 256
#define KDIM (CIN*9)   // 1152

// ---------------- prep: main weight -> fp16 MFMA A-frag layout ----------------
// Wf[(((kch*16 + of)*64 + lane)*8 + e)] = fp16( W[o=of*16+(lane&15)][kc=kch*32+(lane>>4)*8+e] )
// with kc = k*128 + c  (k outer, c inner), W[o][c][k] row-major from reference.
__global__ void k_prep_wf(const float* __restrict__ wgt, unsigned short* __restrict__ Wf) {
    int f = blockIdx.x * 256 + threadIdx.x;   // exactly 294912 threads
    int e = f & 7, l = (f >> 3) & 63, of = (f >> 9) & 15, kch = f >> 13;
    int o = of * 16 + (l & 15);
    int kc = kch * 32 + (l >> 4) * 8 + e;
    int k = kc >> 7, c = kc & 127;
    _Float16 hv = (_Float16)wgt[(size_t)o * KDIM + c * 9 + k];
    Wf[f] = *(unsigned short*)&hv;
}

// ---------------- prep: om_w -> fp16 MFMA A-frag layout (M padded 27->32) -------
__global__ void k_prep_omwf(const float* __restrict__ om_w, unsigned short* __restrict__ omWf) {
    int f = blockIdx.x * 256 + threadIdx.x;   // exactly 36864 threads
    int e = f & 7, l = (f >> 3) & 63, of = (f >> 9) & 1, kch = f >> 10;
    int o = of * 16 + (l & 15);
    int c = (kch & 3) * 32 + (l >> 4) * 8 + e;
    int k = kch >> 2;
    float v = (o < 27) ? om_w[(size_t)o * KDIM + c * 9 + k] : 0.f;
    _Float16 hv = (_Float16)v;
    omWf[f] = *(unsigned short*)&hv;
}

// ---------------- transpose x -> channels-last fp16 ----------------
__global__ __launch_bounds__(256) void k_transpose(const float* __restrict__ x,
                                                   unsigned short* __restrict__ xT) {
    __shared__ unsigned short tile[64][132];
    const int b = blockIdx.x >> 6, y = blockIdx.x & 63;
    const float* xp = x + (size_t)b * CIN * 4096 + y * 64;
    const int w = threadIdx.x & 63, cg = threadIdx.x >> 6;
#pragma unroll
    for (int cc = 0; cc < CIN; cc += 4) {
        int c = cc + cg;
        _Float16 hv = (_Float16)xp[(size_t)c * 4096 + w];
        tile[w][c] = *(unsigned short*)&hv;
    }
    __syncthreads();
    unsigned short* orow = xT + (size_t)(b * 4096 + y * 64) * CIN;
#pragma unroll
    for (int i = 0; i < 8; ++i) {
        int j = threadIdx.x + i * 256;
        int w2 = j >> 5, c2 = (j & 31) * 4;
        ushort4 v = *(ushort4*)&tile[w2][c2];
        ((ushort4*)orow)[j] = v;
    }
}

// ---------------- offset conv via MFMA (fp16 in, f32 acc) ----------------
__global__ __launch_bounds__(256) void k_omconv(const unsigned short* __restrict__ xT_u,
                                                const unsigned short* __restrict__ omWf_u,
                                                const float* __restrict__ om_b,
                                                float* __restrict__ om) {
    const int b = blockIdx.x >> 6, h = blockIdx.x & 63;
    const int tid = threadIdx.x;
    const int wv = tid >> 6, lane = tid & 63;
    const int khalf = lane >> 4, lr = lane & 15;
    const int p = wv * 16 + lr;
    const _Float16* xb = (const _Float16*)xT_u + (size_t)b * 4096 * CIN;
    const h8* Af = (const h8*)omWf_u;

    f32x4 acc0 = (f32x4){0.f, 0.f, 0.f, 0.f};
    f32x4 acc1 = (f32x4){0.f, 0.f, 0.f, 0.f};

#pragma unroll
    for (int k = 0; k < 9; ++k) {
        const int ky = k / 3, kx = k - ky * 3;
        const int y = h + ky - 1, xq = p + kx - 1;
        const bool valid = ((unsigned)y < 64u) && ((unsigned)xq < 64u);
        const _Float16* src = xb + ((y * 64 + xq) * CIN);
#pragma unroll
        for (int cg = 0; cg < 4; ++cg) {
            h8 bf = {};
            if (valid) bf = *(const h8*)(src + cg * 32 + khalf * 8);
            const int kch = k * 4 + cg;
            h8 a0 = Af[(kch * 2 + 0) * 64 + lane];
            h8 a1 = Af[(kch * 2 + 1) * 64 + lane];
            acc0 = __builtin_amdgcn_mfma_f32_16x16x32_f16(a0, bf, acc0, 0, 0, 0);
            acc1 = __builtin_amdgcn_mfma_f32_16x16x32_f16(a1, bf, acc1, 0, 0, 0);
        }
    }

    float* omr = om + ((size_t)(b * 64 + h) * 64 + p) * 27;
#pragma unroll
    for (int r = 0; r < 4; ++r) {
        int row0 = khalf * 4 + r;
        omr[row0] = acc0[r] + om_b[row0];
        int row1 = 16 + khalf * 4 + r;
        if (row1 < 27) omr[row1] = acc1[r] + om_b[row1];
    }
}

// ---------------- fused gather + MFMA GEMM (pipelined, 64-ch chunks) ----------------
// 18 chunks of 64 channels; double-buffered swizzled LDS tile; 1 barrier/chunk;
// next-chunk global loads issued before current chunk's MFMAs.
__global__ __launch_bounds__(512) void k_main(const unsigned short* __restrict__ xT_u,
                                              const float* __restrict__ om,
                                              const unsigned short* __restrict__ Wf_u,
                                              const float* __restrict__ bias,
                                              float* __restrict__ out) {
    const int b = blockIdx.x >> 6, h = blockIdx.x & 63;
    const int tid = threadIdx.x;

    __shared__ int   s_off[4][576];
    __shared__ float s_wt[4][576];
    __shared__ h8    s_tile[2][64 * 8];   // [buf][row*8 + swizzled slot], 64 rows x 64 ch

    // --- sampling metadata for all (k, p) ---
    const float* omr = om + (size_t)(b * 64 + h) * 64 * 27;
    for (int e = tid; e < 576; e += 512) {
        int k = e >> 6, p = e & 63;
        float offx = omr[p * 27 + k];
        float offy = omr[p * 27 + 9 + k];
        float mv   = omr[p * 27 + 18 + k];
        float mask = 1.f / (1.f + __expf(-mv));
        int ky = k / 3, kx = k - ky * 3;
        const float SC = 64.f / 63.f;
        float ix = ((float)(p + kx - 2) + offx) * SC - 0.5f;
        float iy = ((float)(h + ky - 2) + offy) * SC - 0.5f;
        float fx0 = floorf(ix), fy0 = floorf(iy);
        float wx1 = ix - fx0, wx0 = 1.f - wx1;
        float wy1 = iy - fy0, wy0 = 1.f - wy1;
        int x0 = (int)fx0, y0 = (int)fy0;
        int x1 = x0 + 1, y1 = y0 + 1;
        bool vx0 = (unsigned)x0 < 64u, vx1 = (unsigned)x1 < 64u;
        bool vy0 = (unsigned)y0 < 64u, vy1 = (unsigned)y1 < 64u;
        int xc0 = min(max(x0, 0), 63), xc1 = min(max(x1, 0), 63);
        int yc0 = min(max(y0, 0), 63), yc1 = min(max(y1, 0), 63);
        s_off[0][e] = (yc0 * 64 + xc0) * CIN;
        s_off[1][e] = (yc0 * 64 + xc1) * CIN;
        s_off[2][e] = (yc1 * 64 + xc0) * CIN;
        s_off[3][e] = (yc1 * 64 + xc1) * CIN;
        s_wt[0][e] = (vy0 && vx0) ? wy0 * wx0 * mask : 0.f;
        s_wt[1][e] = (vy0 && vx1) ? wy0 * wx1 * mask : 0.f;
        s_wt[2][e] = (vy1 && vx0) ? wy1 * wx0 * mask : 0.f;
        s_wt[3][e] = (vy1 && vx1) ? wy1 * wx1 * mask : 0.f;
    }
    __syncthreads();

    const int p  = tid >> 3;      // gather position 0..63
    const int ci = tid & 7;       // 8-channel slot 0..7
    const _Float16* xb = (const _Float16*)xT_u + (size_t)b * (4096 * CIN);

    const int wv = tid >> 6;      // wave 0..7
    const int lane = tid & 63;
    const int khalf = lane >> 4, lr = lane & 15;
    const h8* Wf8 = (const h8*)Wf_u;

    const int wslot = ci ^ (p & 7);           // swizzled write slot

    f32x4 acc[2][4];
#pragma unroll
    for (int i = 0; i < 2; ++i)
#pragma unroll
        for (int j = 0; j < 4; ++j) acc[i][j] = (f32x4){0.f, 0.f, 0.f, 0.f};

    // ---- prologue: gather chunk 0 into buf 0 ----
    {
        const int e0 = 0 * 64 + p;            // tap 0
        const int cb = 0 * 64 + ci * 8;       // chalf 0
        h8 v00 = *(const h8*)(xb + s_off[0][e0] + cb);
        h8 v01 = *(const h8*)(xb + s_off[1][e0] + cb);
        h8 v10 = *(const h8*)(xb + s_off[2][e0] + cb);
        h8 v11 = *(const h8*)(xb + s_off[3][e0] + cb);
        const float m00 = s_wt[0][e0], m01 = s_wt[1][e0], m10 = s_wt[2][e0], m11 = s_wt[3][e0];
        h8 pk;
#pragma unroll
        for (int j = 0; j < 8; ++j) {
            float r = m00 * (float)v00[j] + m01 * (float)v01[j]
                    + m10 * (float)v10[j] + m11 * (float)v11[j];
            pk[j] = (_Float16)r;
        }
        s_tile[0][p * 8 + wslot] = pk;
    }
    __syncthreads();

    // ---- main loop: 18 chunks, one barrier each ----
    for (int ch = 0; ch < 18; ++ch) {
        const int cur = ch & 1;
        const int nxt = ch + 1;

        // issue next-chunk global loads early (latency hides under MFMAs)
        h8 v00, v01, v10, v11;
        float m00, m01, m10, m11;
        if (nxt < 18) {
            const int kn = nxt >> 1;
            const int e = kn * 64 + p;
            const int cb = (nxt & 1) * 64 + ci * 8;
            v00 = *(const h8*)(xb + s_off[0][e] + cb);
            v01 = *(const h8*)(xb + s_off[1][e] + cb);
            v10 = *(const h8*)(xb + s_off[2][e] + cb);
            v11 = *(const h8*)(xb + s_off[3][e] + cb);
            m00 = s_wt[0][e]; m01 = s_wt[1][e]; m10 = s_wt[2][e]; m11 = s_wt[3][e];
        }

        // MFMAs on current chunk
        const int k = ch >> 1, chalf = ch & 1;
#pragma unroll
        for (int ks = 0; ks < 2; ++ks) {
            const int kch = k * 4 + chalf * 2 + ks;
            h8 a0 = Wf8[(kch * 16 + wv * 2 + 0) * 64 + lane];
            h8 a1 = Wf8[(kch * 16 + wv * 2 + 1) * 64 + lane];
#pragma unroll
            for (int pf = 0; pf < 4; ++pf) {
                const int row = pf * 16 + lr;
                h8 bf = s_tile[cur][row * 8 + ((ks * 4 + khalf) ^ (row & 7))];
                acc[0][pf] = __builtin_amdgcn_mfma_f32_16x16x32_f16(a0, bf, acc[0][pf], 0, 0, 0);
                acc[1][pf] = __builtin_amdgcn_mfma_f32_16x16x32_f16(a1, bf, acc[1][pf], 0, 0, 0);
            }
        }

        // blend + write next chunk to the other buffer
        if (nxt < 18) {
            h8 pk;
#pragma unroll
            for (int j = 0; j < 8; ++j) {
                float r = m00 * (float)v00[j] + m01 * (float)v01[j]
                        + m10 * (float)v10[j] + m11 * (float)v11[j];
                pk[j] = (_Float16)r;
            }
            s_tile[cur ^ 1][p * 8 + wslot] = pk;
        }
        __syncthreads();
    }

    // epilogue: C[o = wv*32 + i*16 + khalf*4 + r][p = pf*16 + lr]
    float* outb = out + (size_t)b * COUT * 4096 + h * 64;
#pragma unroll
    for (int i = 0; i < 2; ++i) {
#pragma unroll
        for (int r = 0; r < 4; ++r) {
            const int o = wv * 32 + i * 16 + khalf * 4 + r;
            const float bo = bias[o];
            float* orow = outb + (size_t)o * 4096;
#pragma unroll
            for (int pf = 0; pf < 4; ++pf)
                orow[pf * 16 + lr] = acc[i][pf][r] + bo;
        }
    }
}

extern "C" void kernel_launch(void* const* d_in, const int* in_sizes, int n_in,
                              void* d_out, int out_size, void* d_ws, size_t ws_size,
                              hipStream_t stream) {
    const float* x    = (const float*)d_in[0];
    const float* om_w = (const float*)d_in[1];
    const float* om_b = (const float*)d_in[2];
    const float* wgt  = (const float*)d_in[3];
    const float* bias = (const float*)d_in[4];
    float* out = (float*)d_out;

    char* ws = (char*)d_ws;
    unsigned short* xT   = (unsigned short*)ws;                      // 4*4096*128*2 = 4194304 B
    float* om            = (float*)(ws + 4194304);                   // 4*4096*27*4  = 1769472 B
    unsigned short* Wf   = (unsigned short*)(ws + 4194304 + 1769472);            // 294912*2 = 589824 B
    unsigned short* omWf = (unsigned short*)(ws + 4194304 + 1769472 + 589824);   // 36864*2  =  73728 B

    k_prep_wf   <<<(COUT * KDIM) / 256, 256, 0, stream>>>(wgt, Wf);
    k_prep_omwf <<<(2 * 16 * KDIM) / 256, 256, 0, stream>>>(om_w, omWf);
    k_transpose <<<256, 256, 0, stream>>>(x, xT);
    k_omconv    <<<256, 256, 0, stream>>>(xT, omWf, om_b, om);
    k_main      <<<256, 512, 0, stream>>>(xT, om, Wf, bias, out);
}

// Round 7
// 47.766 us; speedup vs baseline: 3.2964x; 1.1581x over previous
//
#include <hip/hip_runtime.h>
#include <hip/hip_bf16.h>

typedef _Float16 h4 __attribute__((ext_vector_type(4)));
typedef _Float16 h8 __attribute__((ext_vector_type(8)));
typedef float f32x4 __attribute__((ext_vector_type(4)));

#define CIN 128
#define COUT 256
#define KDIM (CIN*9)   // 1152

// ---------------- merged prep: both weights -> fp16 MFMA A-frag layouts ----------------
// blocks [0,1152): Wf[(((kch*16 + of)*64 + lane)*8 + e)] = fp16(W[o=of*16+(l&15)][kc=kch*32+(l>>4)*8+e])
//   kc = k*128 + c (k outer, c inner), W[o][c][k] row-major.
// blocks [1152,1296): omWf[(((kch*2 + of)*64 + l)*8 + e)] = fp16(om_w[o][c][k]), 0 if o>=27
//   c = (kch&3)*32 + (l>>4)*8 + e, k = kch>>2.
__global__ void k_prep(const float* __restrict__ wgt, const float* __restrict__ om_w,
                       unsigned short* __restrict__ Wf, unsigned short* __restrict__ omWf) {
    int bid = blockIdx.x;
    if (bid < 1152) {
        int f = bid * 256 + threadIdx.x;
        int e = f & 7, l = (f >> 3) & 63, of = (f >> 9) & 15, kch = f >> 13;
        int o = of * 16 + (l & 15);
        int kc = kch * 32 + (l >> 4) * 8 + e;
        int k = kc >> 7, c = kc & 127;
        _Float16 hv = (_Float16)wgt[(size_t)o * KDIM + c * 9 + k];
        Wf[f] = *(unsigned short*)&hv;
    } else {
        int f = (bid - 1152) * 256 + threadIdx.x;   // < 36864
        int e = f & 7, l = (f >> 3) & 63, of = (f >> 9) & 1, kch = f >> 10;
        int o = of * 16 + (l & 15);
        int c = (kch & 3) * 32 + (l >> 4) * 8 + e;
        int k = kch >> 2;
        float v = (o < 27) ? om_w[(size_t)o * KDIM + c * 9 + k] : 0.f;
        _Float16 hv = (_Float16)v;
        omWf[f] = *(unsigned short*)&hv;
    }
}

// ---------------- transpose x -> channels-last fp16 ----------------
// xT[((b*64+y)*64+x)*128 + c] = fp16(x[b][c][y][x])
__global__ __launch_bounds__(256) void k_transpose(const float* __restrict__ x,
                                                   unsigned short* __restrict__ xT) {
    __shared__ unsigned short tile[64][132];
    const int b = blockIdx.x >> 6, y = blockIdx.x & 63;
    const float* xp = x + (size_t)b * CIN * 4096 + y * 64;
    const int w = threadIdx.x & 63, cg = threadIdx.x >> 6;
#pragma unroll
    for (int cc = 0; cc < CIN; cc += 4) {
        int c = cc + cg;
        _Float16 hv = (_Float16)xp[(size_t)c * 4096 + w];
        tile[w][c] = *(unsigned short*)&hv;
    }
    __syncthreads();
    unsigned short* orow = xT + (size_t)(b * 4096 + y * 64) * CIN;
#pragma unroll
    for (int i = 0; i < 8; ++i) {
        int j = threadIdx.x + i * 256;
        int w2 = j >> 5, c2 = (j & 31) * 4;
        ushort4 v = *(ushort4*)&tile[w2][c2];
        ((ushort4*)orow)[j] = v;
    }
}

// ---------------- fused: offset-conv (MFMA) + gather + MFMA GEMM ----------------
__global__ __launch_bounds__(512) void k_fused(const unsigned short* __restrict__ xT_u,
                                               const unsigned short* __restrict__ omWf_u,
                                               const float* __restrict__ om_b,
                                               const unsigned short* __restrict__ Wf_u,
                                               const float* __restrict__ bias,
                                               float* __restrict__ out) {
    const int b = blockIdx.x >> 6, h = blockIdx.x & 63;
    const int tid = threadIdx.x;
    const int wv = tid >> 6, lane = tid & 63;
    const int khalf = lane >> 4, lr = lane & 15;

    __shared__ int   s_off[4][576];
    __shared__ float s_wt[4][576];
    __shared__ h8    s_tile[2][64 * 8];   // [buf][row*8 + swizzled slot]
    __shared__ float red[2][64][28];      // omconv partial sums [tapHalf][pos][oc]

    const _Float16* xb = (const _Float16*)xT_u + (size_t)b * (4096 * CIN);

    // ===== Phase 1: offset conv, 8 waves = 4 position-groups x 2 tap-halves =====
    {
        const h8* Af = (const h8*)omWf_u;
        const int pg = wv & 3, kh2 = wv >> 2;
        const int p = pg * 16 + lr;
        const int k0 = kh2 ? 5 : 0, k1 = kh2 ? 9 : 5;
        f32x4 acc0 = (f32x4){0.f, 0.f, 0.f, 0.f};
        f32x4 acc1 = (f32x4){0.f, 0.f, 0.f, 0.f};
        for (int k = k0; k < k1; ++k) {
            const int ky = k / 3, kx = k - ky * 3;
            const int y = h + ky - 1, xq = p + kx - 1;
            const bool valid = ((unsigned)y < 64u) && ((unsigned)xq < 64u);
            const _Float16* src = xb + ((y * 64 + xq) * CIN);
#pragma unroll
            for (int cg = 0; cg < 4; ++cg) {
                h8 bf = {};
                if (valid) bf = *(const h8*)(src + cg * 32 + khalf * 8);
                const int kch = k * 4 + cg;
                h8 a0 = Af[(kch * 2 + 0) * 64 + lane];
                h8 a1 = Af[(kch * 2 + 1) * 64 + lane];
                acc0 = __builtin_amdgcn_mfma_f32_16x16x32_f16(a0, bf, acc0, 0, 0, 0);
                acc1 = __builtin_amdgcn_mfma_f32_16x16x32_f16(a1, bf, acc1, 0, 0, 0);
            }
        }
        // C layout: col = lr (position), row = khalf*4 + r (+16 for acc1)
#pragma unroll
        for (int r = 0; r < 4; ++r) {
            red[kh2][p][khalf * 4 + r] = acc0[r];
            int row1 = 16 + khalf * 4 + r;
            if (row1 < 27) red[kh2][p][row1] = acc1[r];
        }
    }
    __syncthreads();

    // ===== Phase 2: sampling metadata for all (k, p) =====
    for (int e = tid; e < 576; e += 512) {
        int k = e >> 6, p = e & 63;
        float offx = red[0][p][k]      + red[1][p][k]      + om_b[k];
        float offy = red[0][p][9 + k]  + red[1][p][9 + k]  + om_b[9 + k];
        float mv   = red[0][p][18 + k] + red[1][p][18 + k] + om_b[18 + k];
        float mask = 1.f / (1.f + __expf(-mv));
        int ky = k / 3, kx = k - ky * 3;
        const float SC = 64.f / 63.f;
        float ix = ((float)(p + kx - 2) + offx) * SC - 0.5f;
        float iy = ((float)(h + ky - 2) + offy) * SC - 0.5f;
        float fx0 = floorf(ix), fy0 = floorf(iy);
        float wx1 = ix - fx0, wx0 = 1.f - wx1;
        float wy1 = iy - fy0, wy0 = 1.f - wy1;
        int x0 = (int)fx0, y0 = (int)fy0;
        int x1 = x0 + 1, y1 = y0 + 1;
        bool vx0 = (unsigned)x0 < 64u, vx1 = (unsigned)x1 < 64u;
        bool vy0 = (unsigned)y0 < 64u, vy1 = (unsigned)y1 < 64u;
        int xc0 = min(max(x0, 0), 63), xc1 = min(max(x1, 0), 63);
        int yc0 = min(max(y0, 0), 63), yc1 = min(max(y1, 0), 63);
        s_off[0][e] = (yc0 * 64 + xc0) * CIN;
        s_off[1][e] = (yc0 * 64 + xc1) * CIN;
        s_off[2][e] = (yc1 * 64 + xc0) * CIN;
        s_off[3][e] = (yc1 * 64 + xc1) * CIN;
        s_wt[0][e] = (vy0 && vx0) ? wy0 * wx0 * mask : 0.f;
        s_wt[1][e] = (vy0 && vx1) ? wy0 * wx1 * mask : 0.f;
        s_wt[2][e] = (vy1 && vx0) ? wy1 * wx0 * mask : 0.f;
        s_wt[3][e] = (vy1 && vx1) ? wy1 * wx1 * mask : 0.f;
    }
    __syncthreads();

    // ===== Phase 3: pipelined gather + MFMA GEMM (18 chunks of 64 ch) =====
    const int p  = tid >> 3;      // gather position 0..63
    const int ci = tid & 7;       // 8-channel slot 0..7
    const h8* Wf8 = (const h8*)Wf_u;
    const int wslot = ci ^ (p & 7);

    f32x4 acc[2][4];
#pragma unroll
    for (int i = 0; i < 2; ++i)
#pragma unroll
        for (int j = 0; j < 4; ++j) acc[i][j] = (f32x4){0.f, 0.f, 0.f, 0.f};

    // prologue: gather chunk 0 into buf 0
    {
        const int e0 = p;                     // tap 0
        const int cb = ci * 8;                // chalf 0
        h8 v00 = *(const h8*)(xb + s_off[0][e0] + cb);
        h8 v01 = *(const h8*)(xb + s_off[1][e0] + cb);
        h8 v10 = *(const h8*)(xb + s_off[2][e0] + cb);
        h8 v11 = *(const h8*)(xb + s_off[3][e0] + cb);
        const float m00 = s_wt[0][e0], m01 = s_wt[1][e0], m10 = s_wt[2][e0], m11 = s_wt[3][e0];
        h8 pk;
#pragma unroll
        for (int j = 0; j < 8; ++j) {
            float r = m00 * (float)v00[j] + m01 * (float)v01[j]
                    + m10 * (float)v10[j] + m11 * (float)v11[j];
            pk[j] = (_Float16)r;
        }
        s_tile[0][p * 8 + wslot] = pk;
    }
    __syncthreads();

    for (int ch = 0; ch < 18; ++ch) {
        const int cur = ch & 1;
        const int nxt = ch + 1;

        h8 v00, v01, v10, v11;
        float m00, m01, m10, m11;
        if (nxt < 18) {
            const int kn = nxt >> 1;
            const int e = kn * 64 + p;
            const int cb = (nxt & 1) * 64 + ci * 8;
            v00 = *(const h8*)(xb + s_off[0][e] + cb);
            v01 = *(const h8*)(xb + s_off[1][e] + cb);
            v10 = *(const h8*)(xb + s_off[2][e] + cb);
            v11 = *(const h8*)(xb + s_off[3][e] + cb);
            m00 = s_wt[0][e]; m01 = s_wt[1][e]; m10 = s_wt[2][e]; m11 = s_wt[3][e];
        }

        const int k = ch >> 1, chalf = ch & 1;
#pragma unroll
        for (int ks = 0; ks < 2; ++ks) {
            const int kch = k * 4 + chalf * 2 + ks;
            h8 a0 = Wf8[(kch * 16 + wv * 2 + 0) * 64 + lane];
            h8 a1 = Wf8[(kch * 16 + wv * 2 + 1) * 64 + lane];
#pragma unroll
            for (int pf = 0; pf < 4; ++pf) {
                const int row = pf * 16 + lr;
                h8 bf = s_tile[cur][row * 8 + ((ks * 4 + khalf) ^ (row & 7))];
                acc[0][pf] = __builtin_amdgcn_mfma_f32_16x16x32_f16(a0, bf, acc[0][pf], 0, 0, 0);
                acc[1][pf] = __builtin_amdgcn_mfma_f32_16x16x32_f16(a1, bf, acc[1][pf], 0, 0, 0);
            }
        }

        if (nxt < 18) {
            h8 pk;
#pragma unroll
            for (int j = 0; j < 8; ++j) {
                float r = m00 * (float)v00[j] + m01 * (float)v01[j]
                        + m10 * (float)v10[j] + m11 * (float)v11[j];
                pk[j] = (_Float16)r;
            }
            s_tile[cur ^ 1][p * 8 + wslot] = pk;
        }
        __syncthreads();
    }

    // epilogue: C[o = wv*32 + i*16 + khalf*4 + r][p = pf*16 + lr]
    float* outb = out + (size_t)b * COUT * 4096 + h * 64;
#pragma unroll
    for (int i = 0; i < 2; ++i) {
#pragma unroll
        for (int r = 0; r < 4; ++r) {
            const int o = wv * 32 + i * 16 + khalf * 4 + r;
            const float bo = bias[o];
            float* orow = outb + (size_t)o * 4096;
#pragma unroll
            for (int pf = 0; pf < 4; ++pf)
                orow[pf * 16 + lr] = acc[i][pf][r] + bo;
        }
    }
}

extern "C" void kernel_launch(void* const* d_in, const int* in_sizes, int n_in,
                              void* d_out, int out_size, void* d_ws, size_t ws_size,
                              hipStream_t stream) {
    const float* x    = (const float*)d_in[0];
    const float* om_w = (const float*)d_in[1];
    const float* om_b = (const float*)d_in[2];
    const float* wgt  = (const float*)d_in[3];
    const float* bias = (const float*)d_in[4];
    float* out = (float*)d_out;

    char* ws = (char*)d_ws;
    unsigned short* xT   = (unsigned short*)ws;                      // 4*4096*128*2 = 4194304 B
    unsigned short* Wf   = (unsigned short*)(ws + 4194304);          // 294912*2     =  589824 B
    unsigned short* omWf = (unsigned short*)(ws + 4194304 + 589824); // 36864*2      =   73728 B

    k_prep     <<<1296, 256, 0, stream>>>(wgt, om_w, Wf, omWf);
    k_transpose<<<256, 256, 0, stream>>>(x, xT);
    k_fused    <<<256, 512, 0, stream>>>(xT, omWf, om_b, Wf, bias, out);
}

// Round 9
// 44.484 us; speedup vs baseline: 3.5396x; 1.0738x over previous
//
#include <hip/hip_runtime.h>
#include <hip/hip_bf16.h>

typedef _Float16 h4 __attribute__((ext_vector_type(4)));
typedef _Float16 h8 __attribute__((ext_vector_type(8)));
typedef float f32x4 __attribute__((ext_vector_type(4)));

#define CIN 128
#define COUT 256
#define KDIM (CIN*9)   // 1152

// ---------------- merged prep + transpose ----------------
// blocks [0,256): transpose  xT[((b*64+y)*64+x)*128 + c] = fp16(x[b][c][y][x])
// blocks [256,1408): Wf[(((kch*16 + of)*64 + l)*8 + e)] = fp16(W[o=of*16+(l&15)][kc=kch*32+(l>>4)*8+e])
//   kc = k*128 + c (k outer, c inner), W[o][c][k] row-major.
// blocks [1408,1552): omWf[(((kch*2 + of)*64 + l)*8 + e)] = fp16(om_w[o][c][k]), 0 if o>=27
//   c = (kch&3)*32 + (l>>4)*8 + e, k = kch>>2.
__global__ __launch_bounds__(256) void k_pt(const float* __restrict__ x,
                                            const float* __restrict__ wgt,
                                            const float* __restrict__ om_w,
                                            unsigned short* __restrict__ xT,
                                            unsigned short* __restrict__ Wf,
                                            unsigned short* __restrict__ omWf) {
    __shared__ unsigned short tile[64][132];
    const int bid = blockIdx.x;
    if (bid < 256) {
        const int b = bid >> 6, y = bid & 63;
        const float* xp = x + (size_t)b * CIN * 4096 + y * 64;
        const int w = threadIdx.x & 63, cg = threadIdx.x >> 6;
#pragma unroll
        for (int cc = 0; cc < CIN; cc += 4) {
            int c = cc + cg;
            _Float16 hv = (_Float16)xp[(size_t)c * 4096 + w];
            tile[w][c] = *(unsigned short*)&hv;
        }
        __syncthreads();
        unsigned short* orow = xT + (size_t)(b * 4096 + y * 64) * CIN;
#pragma unroll
        for (int i = 0; i < 8; ++i) {
            int j = threadIdx.x + i * 256;
            int w2 = j >> 5, c2 = (j & 31) * 4;
            ushort4 v = *(ushort4*)&tile[w2][c2];
            ((ushort4*)orow)[j] = v;
        }
    } else if (bid < 1408) {
        int f = (bid - 256) * 256 + threadIdx.x;
        int e = f & 7, l = (f >> 3) & 63, of = (f >> 9) & 15, kch = f >> 13;
        int o = of * 16 + (l & 15);
        int kc = kch * 32 + (l >> 4) * 8 + e;
        int k = kc >> 7, c = kc & 127;
        _Float16 hv = (_Float16)wgt[(size_t)o * KDIM + c * 9 + k];
        Wf[f] = *(unsigned short*)&hv;
    } else {
        int f = (bid - 1408) * 256 + threadIdx.x;   // < 36864
        int e = f & 7, l = (f >> 3) & 63, of = (f >> 9) & 1, kch = f >> 10;
        int o = of * 16 + (l & 15);
        int c = (kch & 3) * 32 + (l >> 4) * 8 + e;
        int k = kch >> 2;
        float v = (o < 27) ? om_w[(size_t)o * KDIM + c * 9 + k] : 0.f;
        _Float16 hv = (_Float16)v;
        omWf[f] = *(unsigned short*)&hv;
    }
}

// ---------------- fused: offset-conv (MFMA) + gather + MFMA GEMM ----------------
// One block per (b, h, half): 32 positions x 256 Cout, 256 threads (4 waves).
__global__ __launch_bounds__(256, 3) void k_fused(const unsigned short* __restrict__ xT_u,
                                                  const unsigned short* __restrict__ omWf_u,
                                                  const float* __restrict__ om_b,
                                                  const unsigned short* __restrict__ Wf_u,
                                                  const float* __restrict__ bias,
                                                  float* __restrict__ out) {
    const int bid = blockIdx.x;
    const int half = bid & 1, h = (bid >> 1) & 63, b = bid >> 7;
    const int p_base = half * 32;
    const int tid = threadIdx.x;
    const int wv = tid >> 6, lane = tid & 63;
    const int khalf = lane >> 4, lr = lane & 15;

    __shared__ int   s_off[4][288];
    __shared__ float s_wt[4][288];
    __shared__ h8    s_tile[2][32 * 8];   // [buf][row*8 + swizzled slot]
    __shared__ float red[2][32][28];      // omconv partials [tapHalf][pos_local][oc]

    const _Float16* xb = (const _Float16*)xT_u + (size_t)b * (4096 * CIN);

    // ===== Phase 1: offset conv, 4 waves = 2 position-groups x 2 tap-halves =====
    {
        const h8* Af = (const h8*)omWf_u;
        const int pg = wv & 1, kh2 = wv >> 1;
        const int pl = pg * 16 + lr;               // local position 0..31
        const int p = p_base + pl;
        const int k0 = kh2 ? 5 : 0, k1 = kh2 ? 9 : 5;
        f32x4 acc0 = (f32x4){0.f, 0.f, 0.f, 0.f};
        f32x4 acc1 = (f32x4){0.f, 0.f, 0.f, 0.f};
        for (int k = k0; k < k1; ++k) {
            const int ky = k / 3, kx = k - ky * 3;
            const int y = h + ky - 1, xq = p + kx - 1;
            const bool valid = ((unsigned)y < 64u) && ((unsigned)xq < 64u);
            const _Float16* src = xb + ((y * 64 + xq) * CIN);
#pragma unroll
            for (int cg = 0; cg < 4; ++cg) {
                h8 bf = {};
                if (valid) bf = *(const h8*)(src + cg * 32 + khalf * 8);
                const int kch = k * 4 + cg;
                h8 a0 = Af[(kch * 2 + 0) * 64 + lane];
                h8 a1 = Af[(kch * 2 + 1) * 64 + lane];
                acc0 = __builtin_amdgcn_mfma_f32_16x16x32_f16(a0, bf, acc0, 0, 0, 0);
                acc1 = __builtin_amdgcn_mfma_f32_16x16x32_f16(a1, bf, acc1, 0, 0, 0);
            }
        }
        // C layout: col = lr (position), row = khalf*4 + r (+16 for acc1)
#pragma unroll
        for (int r = 0; r < 4; ++r) {
            red[kh2][pl][khalf * 4 + r] = acc0[r];
            int row1 = 16 + khalf * 4 + r;
            if (row1 < 27) red[kh2][pl][row1] = acc1[r];
        }
    }
    __syncthreads();

    // ===== Phase 2: sampling metadata for all (k, pl) =====
    for (int e = tid; e < 288; e += 256) {
        int k = e >> 5, pl = e & 31;
        int p = p_base + pl;
        float offx = red[0][pl][k]      + red[1][pl][k]      + om_b[k];
        float offy = red[0][pl][9 + k]  + red[1][pl][9 + k]  + om_b[9 + k];
        float mv   = red[0][pl][18 + k] + red[1][pl][18 + k] + om_b[18 + k];
        float mask = 1.f / (1.f + __expf(-mv));
        int ky = k / 3, kx = k - ky * 3;
        const float SC = 64.f / 63.f;
        float ix = ((float)(p + kx - 2) + offx) * SC - 0.5f;
        float iy = ((float)(h + ky - 2) + offy) * SC - 0.5f;
        float fx0 = floorf(ix), fy0 = floorf(iy);
        float wx1 = ix - fx0, wx0 = 1.f - wx1;
        float wy1 = iy - fy0, wy0 = 1.f - wy1;
        int x0 = (int)fx0, y0 = (int)fy0;
        int x1 = x0 + 1, y1 = y0 + 1;
        bool vx0 = (unsigned)x0 < 64u, vx1 = (unsigned)x1 < 64u;
        bool vy0 = (unsigned)y0 < 64u, vy1 = (unsigned)y1 < 64u;
        int xc0 = min(max(x0, 0), 63), xc1 = min(max(x1, 0), 63);
        int yc0 = min(max(y0, 0), 63), yc1 = min(max(y1, 0), 63);
        s_off[0][e] = (yc0 * 64 + xc0) * CIN;
        s_off[1][e] = (yc0 * 64 + xc1) * CIN;
        s_off[2][e] = (yc1 * 64 + xc0) * CIN;
        s_off[3][e] = (yc1 * 64 + xc1) * CIN;
        s_wt[0][e] = (vy0 && vx0) ? wy0 * wx0 * mask : 0.f;
        s_wt[1][e] = (vy0 && vx1) ? wy0 * wx1 * mask : 0.f;
        s_wt[2][e] = (vy1 && vx0) ? wy1 * wx0 * mask : 0.f;
        s_wt[3][e] = (vy1 && vx1) ? wy1 * wx1 * mask : 0.f;
    }
    __syncthreads();

    // ===== Phase 3: pipelined gather + MFMA GEMM (18 chunks of 64 ch) =====
    const int p  = tid >> 3;      // local gather position 0..31
    const int ci = tid & 7;       // 8-channel slot
    const h8* Wf8 = (const h8*)Wf_u;
    const int wslot = ci ^ (p & 7);

    f32x4 acc[4][2];              // [of-frag i][pos-frag pf]
#pragma unroll
    for (int i = 0; i < 4; ++i)
#pragma unroll
        for (int j = 0; j < 2; ++j) acc[i][j] = (f32x4){0.f, 0.f, 0.f, 0.f};

    // prologue: gather chunk 0 into buf 0
    {
        const int e0 = p;                     // tap 0
        const int cb = ci * 8;                // chalf 0
        h8 v00 = *(const h8*)(xb + s_off[0][e0] + cb);
        h8 v01 = *(const h8*)(xb + s_off[1][e0] + cb);
        h8 v10 = *(const h8*)(xb + s_off[2][e0] + cb);
        h8 v11 = *(const h8*)(xb + s_off[3][e0] + cb);
        const float m00 = s_wt[0][e0], m01 = s_wt[1][e0], m10 = s_wt[2][e0], m11 = s_wt[3][e0];
        h8 pk;
#pragma unroll
        for (int j = 0; j < 8; ++j) {
            float r = m00 * (float)v00[j] + m01 * (float)v01[j]
                    + m10 * (float)v10[j] + m11 * (float)v11[j];
            pk[j] = (_Float16)r;
        }
        s_tile[0][p * 8 + wslot] = pk;
    }
    __syncthreads();

    for (int ch = 0; ch < 18; ++ch) {
        const int cur = ch & 1;
        const int nxt = ch + 1;

        h8 v00, v01, v10, v11;
        float m00, m01, m10, m11;
        if (nxt < 18) {
            const int kn = nxt >> 1;
            const int e = kn * 32 + p;
            const int cb = (nxt & 1) * 64 + ci * 8;
            v00 = *(const h8*)(xb + s_off[0][e] + cb);
            v01 = *(const h8*)(xb + s_off[1][e] + cb);
            v10 = *(const h8*)(xb + s_off[2][e] + cb);
            v11 = *(const h8*)(xb + s_off[3][e] + cb);
            m00 = s_wt[0][e]; m01 = s_wt[1][e]; m10 = s_wt[2][e]; m11 = s_wt[3][e];
        }

        const int k = ch >> 1, chalf = ch & 1;
#pragma unroll
        for (int ks = 0; ks < 2; ++ks) {
            const int kch = k * 4 + chalf * 2 + ks;
            h8 a[4];
#pragma unroll
            for (int i = 0; i < 4; ++i)
                a[i] = Wf8[(kch * 16 + wv * 4 + i) * 64 + lane];
            h8 bf[2];
#pragma unroll
            for (int pf = 0; pf < 2; ++pf) {
                const int row = pf * 16 + lr;
                bf[pf] = s_tile[cur][row * 8 + ((ks * 4 + khalf) ^ (row & 7))];
            }
#pragma unroll
            for (int i = 0; i < 4; ++i)
#pragma unroll
                for (int pf = 0; pf < 2; ++pf)
                    acc[i][pf] = __builtin_amdgcn_mfma_f32_16x16x32_f16(a[i], bf[pf], acc[i][pf], 0, 0, 0);
        }

        if (nxt < 18) {
            h8 pk;
#pragma unroll
            for (int j = 0; j < 8; ++j) {
                float r = m00 * (float)v00[j] + m01 * (float)v01[j]
                        + m10 * (float)v10[j] + m11 * (float)v11[j];
                pk[j] = (_Float16)r;
            }
            s_tile[cur ^ 1][p * 8 + wslot] = pk;
        }
        __syncthreads();
    }

    // epilogue: C[o = wv*64 + i*16 + khalf*4 + r][pos = p_base + pf*16 + lr]
    float* outb = out + (size_t)b * COUT * 4096 + h * 64 + p_base;
#pragma unroll
    for (int i = 0; i < 4; ++i) {
#pragma unroll
        for (int r = 0; r < 4; ++r) {
            const int o = wv * 64 + i * 16 + khalf * 4 + r;
            const float bo = bias[o];
            float* orow = outb + (size_t)o * 4096;
#pragma unroll
            for (int pf = 0; pf < 2; ++pf)
                orow[pf * 16 + lr] = acc[i][pf][r] + bo;
        }
    }
}

extern "C" void kernel_launch(void* const* d_in, const int* in_sizes, int n_in,
                              void* d_out, int out_size, void* d_ws, size_t ws_size,
                              hipStream_t stream) {
    const float* x    = (const float*)d_in[0];
    const float* om_w = (const float*)d_in[1];
    const float* om_b = (const float*)d_in[2];
    const float* wgt  = (const float*)d_in[3];
    const float* bias = (const float*)d_in[4];
    float* out = (float*)d_out;

    char* ws = (char*)d_ws;
    unsigned short* xT   = (unsigned short*)ws;                      // 4*4096*128*2 = 4194304 B
    unsigned short* Wf   = (unsigned short*)(ws + 4194304);          // 294912*2     =  589824 B
    unsigned short* omWf = (unsigned short*)(ws + 4194304 + 589824); // 36864*2      =   73728 B

    k_pt   <<<1552, 256, 0, stream>>>(x, wgt, om_w, xT, Wf, omWf);
    k_fused<<<512, 256, 0, stream>>>(xT, omWf, om_b, Wf, bias, out);
}